// Round 2
// baseline (265.337 us; speedup 1.0000x reference)
//
#include <hip/hip_runtime.h>

// CrossAttentionPlus: out = ( 0.5*softmax(causal(QK^T*s)+mask) + 0.5*supplied ) @ V, head-merged, @Wo + bo
// Normalize-after-mix skipped: denominator == 1 analytically (both mix terms are softmax outputs).
// SCALE (0.125) folded into WqT; MIX (0.5) folded into WvT.
//
// Pipeline (5 launches):
//   1) wtrans: Wq,Wk,Wv,Wo fp32 -> bf16 W^T (K-contiguous), scaled
//   2) cvt:    query,key,value fp32 -> bf16 flat
//   3) gemm_qkv (fused z=0..2, 768 blocks = 3/CU): bf16 GEMM via global_load_lds, writes Qh/Kh [BH,L,64], VTh [BH,64,L]
//   4) attn:   flash softmax + fused supplied branch (diag-specialized causal)
//   5) gemm_out (128x64 tile, 512 blocks): ctx @ WoT + bias -> fp32 d_out

typedef __attribute__((ext_vector_type(8))) short short8;
typedef __attribute__((ext_vector_type(4))) float f32x4;

#define MFMA16(a,b,c) __builtin_amdgcn_mfma_f32_16x16x32_bf16(a,b,c,0,0,0)

__device__ __forceinline__ short f2bf(float f){
  union { float f; unsigned u; } x; x.f = f;
  unsigned r = x.u + 0x7FFFu + ((x.u >> 16) & 1u);
  return (short)(r >> 16);
}

// global -> LDS direct DMA, 16B per lane; LDS dest = wave-uniform base + lane*16.
__device__ __forceinline__ void gload16(const void* g, void* l){
  __builtin_amdgcn_global_load_lds(
      (const __attribute__((address_space(1))) void*)g,
      (__attribute__((address_space(3))) void*)l, 16, 0, 0);
}

// ---------------- weight transpose + convert + scale: out[n][k] = bf16(scl * in[k][n]) ----------------
__global__ __launch_bounds__(256) void wtrans_kernel(
    const float* __restrict__ w0, const float* __restrict__ w1,
    const float* __restrict__ w2, const float* __restrict__ w3,
    short* __restrict__ o0, short* __restrict__ o1,
    short* __restrict__ o2, short* __restrict__ o3)
{
  __shared__ float tile[32][33];
  int z = blockIdx.z;
  const float* in = z==0? w0 : z==1? w1 : z==2? w2 : w3;
  short* out      = z==0? o0 : z==1? o1 : z==2? o2 : o3;
  float scl       = z==0? 0.125f : (z==2? 0.5f : 1.0f);   // SCALE into Wq, MIX into Wv
  int bx = blockIdx.x*32, by = blockIdx.y*32;
  int tx = threadIdx.x, ty = threadIdx.y;   // block (32,8)
  #pragma unroll
  for (int i=0;i<32;i+=8) tile[ty+i][tx] = in[(size_t)(by+ty+i)*1024 + bx+tx];
  __syncthreads();
  #pragma unroll
  for (int i=0;i<32;i+=8) out[(size_t)(bx+ty+i)*1024 + by+tx] = f2bf(scl*tile[tx][ty+i]);
}

// ---------------- input fp32 -> bf16, 8 elems/thread ----------------
__global__ __launch_bounds__(256) void cvt_kernel(
    const float* __restrict__ a, const float* __restrict__ b, const float* __restrict__ c,
    short* __restrict__ oa, short* __restrict__ ob, short* __restrict__ oc)
{
  int z = blockIdx.y;
  const float* s = z==0? a : z==1? b : c;
  short* o       = z==0? oa: z==1? ob: oc;
  size_t i = ((size_t)blockIdx.x*256 + threadIdx.x)*8;
  f32x4 v0 = *(const f32x4*)(s+i);
  f32x4 v1 = *(const f32x4*)(s+i+4);
  short8 r;
  #pragma unroll
  for (int e=0;e<4;e++){ r[e]=f2bf(v0[e]); r[e+4]=f2bf(v1[e]); }
  *(short8*)(o+i) = r;
}

// ---------------- fused QKV projection GEMM ----------------
// C[4096,1024] = A[4096,1024] @ BT[1024,1024]^T ; 128x128 tile, BK=64, 4 waves 2x2.
// LDS staged via global_load_lds with pre-swizzled source (linear LDS dest + XOR-swizzled read).
__global__ __launch_bounds__(256) void gemm_qkv_kernel(
    const short* __restrict__ Qb, const short* __restrict__ Kb, const short* __restrict__ Vb,
    const short* __restrict__ WqT, const short* __restrict__ WkT, const short* __restrict__ WvT,
    short* __restrict__ Qh, short* __restrict__ Kh, short* __restrict__ VTh)
{
  __shared__ short Asm[128*64];
  __shared__ short Bsm[128*64];
  int z = blockIdx.z;
  const short* A  = z==0? Qb : z==1? Kb : Vb;
  const short* BT = z==0? WqT: z==1? WkT: WvT;
  int tid = threadIdx.x, lane = tid & 63, wv = tid >> 6;
  int wm = (wv >> 1) * 64, wn = (wv & 1) * 64;
  int bm = blockIdx.y * 128, bn = blockIdx.x * 128;

  const f32x4 z4 = {0.f,0.f,0.f,0.f};
  f32x4 acc[4][4];
  #pragma unroll
  for (int i=0;i<4;i++)
    #pragma unroll
    for (int j=0;j<4;j++) acc[i][j] = z4;

  for (int kt=0; kt<16; kt++){
    __syncthreads();   // prior compute done reading LDS
    #pragma unroll
    for (int i=0;i<4;i++){
      int row0 = wv*32 + i*8;                 // wave-uniform
      int row  = row0 + (lane>>3);
      int col  = ((lane&7) ^ (row&7)) * 8;    // pre-swizzled source column
      gload16(A  + (size_t)(bm+row)*1024 + kt*64 + col, Asm + row0*64);
      gload16(BT + (size_t)(bn+row)*1024 + kt*64 + col, Bsm + row0*64);
    }
    __syncthreads();   // drains vmcnt -> staged data visible
    #pragma unroll
    for (int kc=0;kc<2;kc++){
      short8 af[4], bf[4];
      #pragma unroll
      for (int i=0;i<4;i++){
        int ra = wm + i*16 + (lane&15);
        af[i] = *(const short8*)((const char*)Asm + ra*128 + ((kc*64 + ((lane>>4)*16)) ^ ((ra&7)<<4)));
        int rb = wn + i*16 + (lane&15);
        bf[i] = *(const short8*)((const char*)Bsm + rb*128 + ((kc*64 + ((lane>>4)*16)) ^ ((rb&7)<<4)));
      }
      #pragma unroll
      for (int i=0;i<4;i++)
        #pragma unroll
        for (int j=0;j<4;j++)
          acc[i][j] = MFMA16(af[i], bf[j], acc[i][j]);
    }
  }

  #pragma unroll
  for (int i=0;i<4;i++){
    #pragma unroll
    for (int j=0;j<4;j++){
      #pragma unroll
      for (int r=0;r<4;r++){
        int m = bm + wm + i*16 + ((lane>>4)*4) + r;
        int n = bn + wn + j*16 + (lane&15);
        int b = m >> 10, l = m & 1023, h = n >> 6, d = n & 63;
        int bh = b*16 + h;
        short bv = f2bf(acc[i][j][r]);
        if (z == 2)      VTh[((size_t)(bh*64 + d) << 10) + l] = bv;
        else if (z == 1) Kh[((size_t)(bh << 10) + l)*64 + d] = bv;
        else             Qh[((size_t)(bh << 10) + l)*64 + d] = bv;
      }
    }
  }
}

// ---------------- fused attention ----------------
// grid (qb=16, bh=64), 4 waves; wave owns 16 q-rows. V pre-scaled by 0.5, Q pre-scaled by 0.125.
// ctx[b][q][h*64+d] = o_loc/l_run + o_sup
__global__ __launch_bounds__(256) void attn_kernel(
    const short* __restrict__ Qh, const short* __restrict__ Kh,
    const short* __restrict__ VTh, const float* __restrict__ amask,
    const float* __restrict__ sup, short* __restrict__ ctx)
{
  __shared__ short Ksm[64*64];      // [k][d]  swizzled
  __shared__ short Vsm[64*64];      // [d][k]  swizzled
  __shared__ short Psm[4][16*64];   // per-wave P, swizzled
  int tid = threadIdx.x, lane = tid & 63, wv = tid >> 6;
  int qb = blockIdx.x, bh = blockIdx.y;
  int b = bh >> 4, h = bh & 15;
  int q0w = qb*64 + wv*16;

  const f32x4 z4 = {0.f,0.f,0.f,0.f};
  short8 qf[2];
  {
    const short* qp = Qh + ((size_t)bh*1024 + q0w + (lane&15))*64 + (lane>>4)*8;
    qf[0] = *(const short8*)qp;
    qf[1] = *(const short8*)(qp + 32);
  }
  f32x4 o_loc[4], o_sup[4];
  #pragma unroll
  for (int i=0;i<4;i++){ o_loc[i]=z4; o_sup[i]=z4; }
  float m_run[4], l_run[4];
  #pragma unroll
  for (int j=0;j<4;j++){ m_run[j]=-3e38f; l_run[j]=0.f; }

  const float* supq  = sup   + ((size_t)bh << 20);
  const float* maskb = amask + ((size_t)b  << 20);

  for (int t=0; t<=qb; t++){
    __syncthreads();
    #pragma unroll
    for (int i=0;i<2;i++){
      int row0 = wv*16 + i*8;
      int row  = row0 + (lane>>3);
      int col  = ((lane&7) ^ (row&7)) * 8;
      gload16(Kh  + ((size_t)bh*1024 + t*64 + row)*64 + col, Ksm + row0*64);
      gload16(VTh + ((size_t)(bh*64 + row))*1024 + t*64 + col, Vsm + row0*64);
    }
    __syncthreads();

    int k0 = t*64;
    bool diag = (t == qb);      // block-uniform
    // S = Q K^T  (q pre-scaled by 0.125)
    f32x4 s[4];
    #pragma unroll
    for (int ni=0;ni<4;ni++) s[ni]=z4;
    #pragma unroll
    for (int kc=0;kc<2;kc++){
      #pragma unroll
      for (int ni=0;ni<4;ni++){
        int row = ni*16 + (lane&15);
        short8 kf = *(const short8*)((const char*)Ksm + row*128 + ((kc*64 + ((lane>>4)*16)) ^ ((row&7)<<4)));
        s[ni] = MFMA16(qf[kc], kf, s[ni]);
      }
    }
    // mask + online softmax (row across 16 lanes)
    float sv[4][4];
    #pragma unroll
    for (int j=0;j<4;j++){
      int q = q0w + (lane>>4)*4 + j;
      const float* mrow = maskb + ((size_t)q<<10) + k0 + (lane&15);
      float x[4];
      #pragma unroll
      for (int ni=0;ni<4;ni++) x[ni] = s[ni][j] + mrow[ni*16];
      if (diag){
        #pragma unroll
        for (int ni=0;ni<4;ni++){
          int k = k0 + ni*16 + (lane&15);
          if (k > q) x[ni] = -1e30f;
        }
      }
      float rm = fmaxf(fmaxf(x[0],x[1]), fmaxf(x[2],x[3]));
      rm = fmaxf(rm, __shfl_xor(rm,1));
      rm = fmaxf(rm, __shfl_xor(rm,2));
      rm = fmaxf(rm, __shfl_xor(rm,4));
      rm = fmaxf(rm, __shfl_xor(rm,8));
      float mn = fmaxf(m_run[j], rm);
      float al = __expf(m_run[j] - mn);
      m_run[j] = mn;
      float sum = 0.f;
      #pragma unroll
      for (int ni=0;ni<4;ni++){
        float p = __expf(x[ni] - mn);
        sv[ni][j] = p;
        sum += p;
      }
      sum += __shfl_xor(sum,1); sum += __shfl_xor(sum,2);
      sum += __shfl_xor(sum,4); sum += __shfl_xor(sum,8);
      l_run[j] = l_run[j]*al + sum;
      #pragma unroll
      for (int dn=0;dn<4;dn++) o_loc[dn][j] *= al;
    }
    // P -> LDS (bf16, swizzled): C-layout write / A-layout read
    #pragma unroll
    for (int ni=0;ni<4;ni++){
      #pragma unroll
      for (int j=0;j<4;j++){
        int row = (lane>>4)*4 + j, col = ni*16 + (lane&15);
        *(short*)((char*)Psm[wv] + row*128 + ((2*col) ^ ((row&7)<<4))) = f2bf(sv[ni][j]);
      }
    }
    // PV (local) + supplied branch (A-frags straight from global fp32, streamed nontemporal)
    #pragma unroll
    for (int kc=0;kc<2;kc++){
      int prow = lane & 15;
      short8 pf = *(const short8*)((const char*)Psm[wv] + prow*128 + ((kc*64 + ((lane>>4)*16)) ^ ((prow&7)<<4)));
      int q  = q0w + (lane&15);
      int kb = k0 + kc*32 + (lane>>4)*8;
      const float* sp = supq + ((size_t)q<<10) + kb;
      f32x4 s0 = __builtin_nontemporal_load((const f32x4*)sp);
      f32x4 s1 = __builtin_nontemporal_load((const f32x4*)(sp+4));
      short8 sf;
      if (diag){
        #pragma unroll
        for (int e=0;e<8;e++){
          float vv = (e<4) ? s0[e] : s1[e-4];
          sf[e] = (kb + e > q) ? (short)0 : f2bf(vv);
        }
      } else {
        #pragma unroll
        for (int e=0;e<4;e++){ sf[e]=f2bf(s0[e]); sf[e+4]=f2bf(s1[e]); }
      }
      #pragma unroll
      for (int dn=0;dn<4;dn++){
        int vrow = dn*16 + (lane&15);
        short8 vf = *(const short8*)((const char*)Vsm + vrow*128 + ((kc*64 + ((lane>>4)*16)) ^ ((vrow&7)<<4)));
        o_loc[dn] = MFMA16(pf, vf, o_loc[dn]);
        o_sup[dn] = MFMA16(sf, vf, o_sup[dn]);
      }
    }
  }

  #pragma unroll
  for (int j=0;j<4;j++){
    float rl = 1.0f / l_run[j];
    int q = q0w + (lane>>4)*4 + j;
    #pragma unroll
    for (int dn=0;dn<4;dn++){
      int d = dn*16 + (lane&15);
      ctx[((size_t)b*1024 + q)*1024 + h*64 + d] = f2bf(o_loc[dn][j]*rl + o_sup[dn][j]);
    }
  }
}

// ---------------- output GEMM: out[4096,1024] = Ctx @ WoT^T + bias ; 128x64 tile ----------------
__global__ __launch_bounds__(256) void gemm_out_kernel(
    const short* __restrict__ Ctx, const short* __restrict__ WoT,
    float* __restrict__ out, const float* __restrict__ bias)
{
  __shared__ short Asm[128*64];
  __shared__ short Bsm[64*64];
  int tid = threadIdx.x, lane = tid & 63, wv = tid >> 6;
  int wm = wv * 32;                     // 4 waves split M; each wave 32x64
  int bm = blockIdx.y * 128, bn = blockIdx.x * 64;

  const f32x4 z4 = {0.f,0.f,0.f,0.f};
  f32x4 acc[2][4];
  #pragma unroll
  for (int i=0;i<2;i++)
    #pragma unroll
    for (int j=0;j<4;j++) acc[i][j] = z4;

  for (int kt=0; kt<16; kt++){
    __syncthreads();
    #pragma unroll
    for (int i=0;i<4;i++){
      int row0 = wv*32 + i*8;
      int row  = row0 + (lane>>3);
      int col  = ((lane&7) ^ (row&7)) * 8;
      gload16(Ctx + (size_t)(bm+row)*1024 + kt*64 + col, Asm + row0*64);
    }
    #pragma unroll
    for (int i=0;i<2;i++){
      int row0 = wv*16 + i*8;
      int row  = row0 + (lane>>3);
      int col  = ((lane&7) ^ (row&7)) * 8;
      gload16(WoT + (size_t)(bn+row)*1024 + kt*64 + col, Bsm + row0*64);
    }
    __syncthreads();
    #pragma unroll
    for (int kc=0;kc<2;kc++){
      short8 af[2], bf[4];
      #pragma unroll
      for (int i=0;i<2;i++){
        int ra = wm + i*16 + (lane&15);
        af[i] = *(const short8*)((const char*)Asm + ra*128 + ((kc*64 + ((lane>>4)*16)) ^ ((ra&7)<<4)));
      }
      #pragma unroll
      for (int j=0;j<4;j++){
        int rb = j*16 + (lane&15);
        bf[j] = *(const short8*)((const char*)Bsm + rb*128 + ((kc*64 + ((lane>>4)*16)) ^ ((rb&7)<<4)));
      }
      #pragma unroll
      for (int i=0;i<2;i++)
        #pragma unroll
        for (int j=0;j<4;j++)
          acc[i][j] = MFMA16(af[i], bf[j], acc[i][j]);
    }
  }

  #pragma unroll
  for (int i=0;i<2;i++){
    #pragma unroll
    for (int j=0;j<4;j++){
      #pragma unroll
      for (int r=0;r<4;r++){
        int m = bm + wm + i*16 + ((lane>>4)*4) + r;
        int n = bn + j*16 + (lane&15);
        out[(size_t)m*1024 + n] = acc[i][j][r] + bias[n];
      }
    }
  }
}

// ---------------- launch ----------------
extern "C" void kernel_launch(void* const* d_in, const int* in_sizes, int n_in,
                              void* d_out, int out_size, void* d_ws, size_t ws_size,
                              hipStream_t stream) {
  const float* query = (const float*)d_in[0];
  const float* key   = (const float*)d_in[1];
  const float* value = (const float*)d_in[2];
  const float* amask = (const float*)d_in[3];
  const float* sup   = (const float*)d_in[4];
  const float* Wq    = (const float*)d_in[5];
  const float* Wk    = (const float*)d_in[6];
  const float* Wv    = (const float*)d_in[7];
  const float* Wo    = (const float*)d_in[8];
  const float* bo    = (const float*)d_in[9];
  // d_in[10] = causal_mask (deterministic triu(1)) -- applied analytically.

  char* ws = (char*)d_ws;
  const size_t MB = 1u<<20;
  short* WqT = (short*)(ws + 0*MB);
  short* WkT = (short*)(ws + 2*MB);
  short* WvT = (short*)(ws + 4*MB);
  short* WoT = (short*)(ws + 6*MB);
  short* Qb  = (short*)(ws + 8*MB);    // bf16 [4096][1024]
  short* Kb  = (short*)(ws + 16*MB);
  short* Vb  = (short*)(ws + 24*MB);
  short* Qh  = (short*)(ws + 32*MB);   // [64][1024][64]
  short* Kh  = (short*)(ws + 40*MB);   // [64][1024][64]
  short* VTh = (short*)(ws + 48*MB);   // [64][64][1024]
  short* Ctx = (short*)(ws + 56*MB);   // [4096][1024]
  // 64 MB of d_ws total

  wtrans_kernel<<<dim3(32,32,4), dim3(32,8), 0, stream>>>(Wq,Wk,Wv,Wo, WqT,WkT,WvT,WoT);
  cvt_kernel<<<dim3(2048,3), 256, 0, stream>>>(query,key,value, Qb,Kb,Vb);
  gemm_qkv_kernel<<<dim3(8,32,3), 256, 0, stream>>>(Qb,Kb,Vb, WqT,WkT,WvT, Qh,Kh,VTh);
  attn_kernel<<<dim3(16,64), 256, 0, stream>>>(Qh, Kh, VTh, amask, sup, Ctx);
  gemm_out_kernel<<<dim3(16,32), 256, 0, stream>>>(Ctx, WoT, (float*)d_out, bo);
}

// Round 3
// 208.292 us; speedup vs baseline: 1.2739x; 1.2739x over previous
//
#include <hip/hip_runtime.h>

// CrossAttentionPlus: out = ( 0.5*softmax(causal(QK^T*s)+mask) + 0.5*supplied ) @ V, head-merged, @Wo + bo
// Normalize-after-mix skipped: denominator == 1 analytically (both mix terms are softmax outputs).
// SCALE (0.125) folded into WqT; MIX (0.5) folded into WvT.
//
// Pipeline (5 launches):
//   1) wtrans: Wq,Wk,Wv,Wo fp32 -> bf16 W^T (K-contiguous), scaled
//   2) cvt:    query,key,value fp32 -> bf16 flat
//   3) gemm_qkv (fused z=0..2, 768 blocks = 3/CU): bf16 GEMM via global_load_lds
//   4) attn:   flash softmax + fused supplied branch; dbuf K/V LDS + early-issue sup/mask prefetch
//   5) gemm_out (128x64 tile, 512 blocks): ctx @ WoT + bias -> fp32 d_out

typedef __attribute__((ext_vector_type(8))) short short8;
typedef __attribute__((ext_vector_type(4))) float f32x4;

#define MFMA16(a,b,c) __builtin_amdgcn_mfma_f32_16x16x32_bf16(a,b,c,0,0,0)

__device__ __forceinline__ short f2bf(float f){
  union { float f; unsigned u; } x; x.f = f;
  unsigned r = x.u + 0x7FFFu + ((x.u >> 16) & 1u);
  return (short)(r >> 16);
}

// global -> LDS direct DMA, 16B per lane; LDS dest = wave-uniform base + lane*16.
__device__ __forceinline__ void gload16(const void* g, void* l){
  __builtin_amdgcn_global_load_lds(
      (const __attribute__((address_space(1))) void*)g,
      (__attribute__((address_space(3))) void*)l, 16, 0, 0);
}

// ---------------- weight transpose + convert + scale: out[n][k] = bf16(scl * in[k][n]) ----------------
__global__ __launch_bounds__(256) void wtrans_kernel(
    const float* __restrict__ w0, const float* __restrict__ w1,
    const float* __restrict__ w2, const float* __restrict__ w3,
    short* __restrict__ o0, short* __restrict__ o1,
    short* __restrict__ o2, short* __restrict__ o3)
{
  __shared__ float tile[32][33];
  int z = blockIdx.z;
  const float* in = z==0? w0 : z==1? w1 : z==2? w2 : w3;
  short* out      = z==0? o0 : z==1? o1 : z==2? o2 : o3;
  float scl       = z==0? 0.125f : (z==2? 0.5f : 1.0f);   // SCALE into Wq, MIX into Wv
  int bx = blockIdx.x*32, by = blockIdx.y*32;
  int tx = threadIdx.x, ty = threadIdx.y;   // block (32,8)
  #pragma unroll
  for (int i=0;i<32;i+=8) tile[ty+i][tx] = in[(size_t)(by+ty+i)*1024 + bx+tx];
  __syncthreads();
  #pragma unroll
  for (int i=0;i<32;i+=8) out[(size_t)(bx+ty+i)*1024 + by+tx] = f2bf(scl*tile[tx][ty+i]);
}

// ---------------- input fp32 -> bf16, 8 elems/thread ----------------
__global__ __launch_bounds__(256) void cvt_kernel(
    const float* __restrict__ a, const float* __restrict__ b, const float* __restrict__ c,
    short* __restrict__ oa, short* __restrict__ ob, short* __restrict__ oc)
{
  int z = blockIdx.y;
  const float* s = z==0? a : z==1? b : c;
  short* o       = z==0? oa: z==1? ob: oc;
  size_t i = ((size_t)blockIdx.x*256 + threadIdx.x)*8;
  f32x4 v0 = *(const f32x4*)(s+i);
  f32x4 v1 = *(const f32x4*)(s+i+4);
  short8 r;
  #pragma unroll
  for (int e=0;e<4;e++){ r[e]=f2bf(v0[e]); r[e+4]=f2bf(v1[e]); }
  *(short8*)(o+i) = r;
}

// ---------------- fused QKV projection GEMM ----------------
// C[4096,1024] = A[4096,1024] @ BT[1024,1024]^T ; 128x128 tile, BK=64, 4 waves 2x2.
__global__ __launch_bounds__(256) void gemm_qkv_kernel(
    const short* __restrict__ Qb, const short* __restrict__ Kb, const short* __restrict__ Vb,
    const short* __restrict__ WqT, const short* __restrict__ WkT, const short* __restrict__ WvT,
    short* __restrict__ Qh, short* __restrict__ Kh, short* __restrict__ VTh)
{
  __shared__ short Asm[128*64];
  __shared__ short Bsm[128*64];
  int z = blockIdx.z;
  const short* A  = z==0? Qb : z==1? Kb : Vb;
  const short* BT = z==0? WqT: z==1? WkT: WvT;
  int tid = threadIdx.x, lane = tid & 63, wv = tid >> 6;
  int wm = (wv >> 1) * 64, wn = (wv & 1) * 64;
  int bm = blockIdx.y * 128, bn = blockIdx.x * 128;

  const f32x4 z4 = {0.f,0.f,0.f,0.f};
  f32x4 acc[4][4];
  #pragma unroll
  for (int i=0;i<4;i++)
    #pragma unroll
    for (int j=0;j<4;j++) acc[i][j] = z4;

  for (int kt=0; kt<16; kt++){
    __syncthreads();
    #pragma unroll
    for (int i=0;i<4;i++){
      int row0 = wv*32 + i*8;                 // wave-uniform
      int row  = row0 + (lane>>3);
      int col  = ((lane&7) ^ (row&7)) * 8;    // pre-swizzled source column
      gload16(A  + (size_t)(bm+row)*1024 + kt*64 + col, Asm + row0*64);
      gload16(BT + (size_t)(bn+row)*1024 + kt*64 + col, Bsm + row0*64);
    }
    __syncthreads();
    #pragma unroll
    for (int kc=0;kc<2;kc++){
      short8 af[4], bf[4];
      #pragma unroll
      for (int i=0;i<4;i++){
        int ra = wm + i*16 + (lane&15);
        af[i] = *(const short8*)((const char*)Asm + ra*128 + ((kc*64 + ((lane>>4)*16)) ^ ((ra&7)<<4)));
        int rb = wn + i*16 + (lane&15);
        bf[i] = *(const short8*)((const char*)Bsm + rb*128 + ((kc*64 + ((lane>>4)*16)) ^ ((rb&7)<<4)));
      }
      #pragma unroll
      for (int i=0;i<4;i++)
        #pragma unroll
        for (int j=0;j<4;j++)
          acc[i][j] = MFMA16(af[i], bf[j], acc[i][j]);
    }
  }

  #pragma unroll
  for (int i=0;i<4;i++){
    #pragma unroll
    for (int j=0;j<4;j++){
      #pragma unroll
      for (int r=0;r<4;r++){
        int m = bm + wm + i*16 + ((lane>>4)*4) + r;
        int n = bn + wn + j*16 + (lane&15);
        int b = m >> 10, l = m & 1023, h = n >> 6, d = n & 63;
        int bh = b*16 + h;
        short bv = f2bf(acc[i][j][r]);
        if (z == 2)      VTh[((size_t)(bh*64 + d) << 10) + l] = bv;
        else if (z == 1) Kh[((size_t)(bh << 10) + l)*64 + d] = bv;
        else             Qh[((size_t)(bh << 10) + l)*64 + d] = bv;
      }
    }
  }
}

// ---------------- fused attention ----------------
// grid (qb=16, bh=64), 4 waves; wave owns 16 q-rows. V pre-scaled by 0.5, Q pre-scaled by 0.125.
// Double-buffered K/V LDS (gload16 for t+1 issued during compute of t, drained by next barrier);
// sup (NT) and mask loads issued at iteration top, consumed after QK^T/softmax (T14).
__global__ __launch_bounds__(256) void attn_kernel(
    const short* __restrict__ Qh, const short* __restrict__ Kh,
    const short* __restrict__ VTh, const float* __restrict__ amask,
    const float* __restrict__ sup, short* __restrict__ ctx)
{
  __shared__ short Ksm[2][64*64];   // [k][d]  swizzled
  __shared__ short Vsm[2][64*64];   // [d][k]  swizzled
  __shared__ short Psm[4][16*64];   // per-wave P, swizzled (lgkm-ordered, no barrier needed)
  int tid = threadIdx.x, lane = tid & 63, wv = tid >> 6;
  int qb = blockIdx.x, bh = blockIdx.y;
  int b = bh >> 4, h = bh & 15;
  int q0w = qb*64 + wv*16;

  const f32x4 z4 = {0.f,0.f,0.f,0.f};
  short8 qf[2];
  {
    const short* qp = Qh + ((size_t)bh*1024 + q0w + (lane&15))*64 + (lane>>4)*8;
    qf[0] = *(const short8*)qp;
    qf[1] = *(const short8*)(qp + 32);
  }
  f32x4 o_loc[4], o_sup[4];
  #pragma unroll
  for (int i=0;i<4;i++){ o_loc[i]=z4; o_sup[i]=z4; }
  float m_run[4], l_run[4];
  #pragma unroll
  for (int j=0;j<4;j++){ m_run[j]=-3e38f; l_run[j]=0.f; }

  const float* supq  = sup   + ((size_t)bh << 20);
  const float* maskb = amask + ((size_t)b  << 20);

  auto stage = [&](int t, int buf){
    #pragma unroll
    for (int i=0;i<2;i++){
      int row0 = wv*16 + i*8;
      int row  = row0 + (lane>>3);
      int col  = ((lane&7) ^ (row&7)) * 8;
      gload16(Kh  + ((size_t)bh*1024 + t*64 + row)*64 + col, Ksm[buf] + row0*64);
      gload16(VTh + ((size_t)(bh*64 + row))*1024 + t*64 + col, Vsm[buf] + row0*64);
    }
  };

  stage(0, 0);
  int cur = 0;
  for (int t=0; t<=qb; t++){
    __syncthreads();              // drains vmcnt -> Ksm/Vsm[cur] ready

    int k0 = t*64;
    bool diag = (t == qb);        // block-uniform
    int qme = q0w + (lane&15);    // this lane's sup q-row (A-frag role)

    // --- early-issue: sup (NT) + mask loads for THIS tile; consumed post-QK^T ---
    const float* sp = supq + ((size_t)qme<<10) + k0 + (lane>>4)*8;
    f32x4 sA0 = __builtin_nontemporal_load((const f32x4*)sp);
    f32x4 sA1 = __builtin_nontemporal_load((const f32x4*)(sp+4));
    f32x4 sB0 = __builtin_nontemporal_load((const f32x4*)(sp+32));
    f32x4 sB1 = __builtin_nontemporal_load((const f32x4*)(sp+36));
    float mreg[4][4];
    {
      int qj0 = q0w + (lane>>4)*4;
      #pragma unroll
      for (int j=0;j<4;j++){
        const float* mrow = maskb + ((size_t)(qj0+j)<<10) + k0 + (lane&15);
        #pragma unroll
        for (int ni=0;ni<4;ni++) mreg[j][ni] = mrow[ni*16];
      }
    }

    // --- prefetch next K/V tile into the other LDS buffer (lands during compute) ---
    if (t < qb) stage(t+1, cur^1);

    // --- S = Q K^T (q pre-scaled by 0.125) ---
    f32x4 s[4];
    #pragma unroll
    for (int ni=0;ni<4;ni++) s[ni]=z4;
    #pragma unroll
    for (int kc=0;kc<2;kc++){
      #pragma unroll
      for (int ni=0;ni<4;ni++){
        int row = ni*16 + (lane&15);
        short8 kf = *(const short8*)((const char*)Ksm[cur] + row*128 + ((kc*64 + ((lane>>4)*16)) ^ ((row&7)<<4)));
        s[ni] = MFMA16(qf[kc], kf, s[ni]);
      }
    }
    // --- mask + online softmax (row across 16 lanes) ---
    float sv[4][4];
    #pragma unroll
    for (int j=0;j<4;j++){
      int q = q0w + (lane>>4)*4 + j;
      float x[4];
      #pragma unroll
      for (int ni=0;ni<4;ni++) x[ni] = s[ni][j] + mreg[j][ni];
      if (diag){
        #pragma unroll
        for (int ni=0;ni<4;ni++){
          int k = k0 + ni*16 + (lane&15);
          if (k > q) x[ni] = -1e30f;
        }
      }
      float rm = fmaxf(fmaxf(x[0],x[1]), fmaxf(x[2],x[3]));
      rm = fmaxf(rm, __shfl_xor(rm,1));
      rm = fmaxf(rm, __shfl_xor(rm,2));
      rm = fmaxf(rm, __shfl_xor(rm,4));
      rm = fmaxf(rm, __shfl_xor(rm,8));
      float mn = fmaxf(m_run[j], rm);
      float al = __expf(m_run[j] - mn);
      m_run[j] = mn;
      float sum = 0.f;
      #pragma unroll
      for (int ni=0;ni<4;ni++){
        float p = __expf(x[ni] - mn);
        sv[ni][j] = p;
        sum += p;
      }
      sum += __shfl_xor(sum,1); sum += __shfl_xor(sum,2);
      sum += __shfl_xor(sum,4); sum += __shfl_xor(sum,8);
      l_run[j] = l_run[j]*al + sum;
      #pragma unroll
      for (int dn=0;dn<4;dn++) o_loc[dn][j] *= al;
    }
    // --- P -> per-wave LDS (bf16, swizzled): C-layout write / A-layout read ---
    #pragma unroll
    for (int ni=0;ni<4;ni++){
      #pragma unroll
      for (int j=0;j<4;j++){
        int row = (lane>>4)*4 + j, col = ni*16 + (lane&15);
        *(short*)((char*)Psm[wv] + row*128 + ((2*col) ^ ((row&7)<<4))) = f2bf(sv[ni][j]);
      }
    }
    // --- PV (local) + supplied branch from prefetched regs ---
    #pragma unroll
    for (int kc=0;kc<2;kc++){
      int prow = lane & 15;
      short8 pf = *(const short8*)((const char*)Psm[wv] + prow*128 + ((kc*64 + ((lane>>4)*16)) ^ ((prow&7)<<4)));
      int kb = k0 + kc*32 + (lane>>4)*8;
      f32x4 s0 = kc ? sB0 : sA0;
      f32x4 s1 = kc ? sB1 : sA1;
      short8 sf;
      if (diag){
        #pragma unroll
        for (int e=0;e<8;e++){
          float vv = (e<4) ? s0[e] : s1[e-4];
          sf[e] = (kb + e > qme) ? (short)0 : f2bf(vv);
        }
      } else {
        #pragma unroll
        for (int e=0;e<4;e++){ sf[e]=f2bf(s0[e]); sf[e+4]=f2bf(s1[e]); }
      }
      #pragma unroll
      for (int dn=0;dn<4;dn++){
        int vrow = dn*16 + (lane&15);
        short8 vf = *(const short8*)((const char*)Vsm[cur] + vrow*128 + ((kc*64 + ((lane>>4)*16)) ^ ((vrow&7)<<4)));
        o_loc[dn] = MFMA16(pf, vf, o_loc[dn]);
        o_sup[dn] = MFMA16(sf, vf, o_sup[dn]);
      }
    }
    cur ^= 1;
  }

  #pragma unroll
  for (int j=0;j<4;j++){
    float rl = 1.0f / l_run[j];
    int q = q0w + (lane>>4)*4 + j;
    #pragma unroll
    for (int dn=0;dn<4;dn++){
      int d = dn*16 + (lane&15);
      ctx[((size_t)b*1024 + q)*1024 + h*64 + d] = f2bf(o_loc[dn][j]*rl + o_sup[dn][j]);
    }
  }
}

// ---------------- output GEMM: out[4096,1024] = Ctx @ WoT^T + bias ; 128x64 tile ----------------
__global__ __launch_bounds__(256) void gemm_out_kernel(
    const short* __restrict__ Ctx, const short* __restrict__ WoT,
    float* __restrict__ out, const float* __restrict__ bias)
{
  __shared__ short Asm[128*64];
  __shared__ short Bsm[64*64];
  int tid = threadIdx.x, lane = tid & 63, wv = tid >> 6;
  int wm = wv * 32;                     // 4 waves split M; each wave 32x64
  int bm = blockIdx.y * 128, bn = blockIdx.x * 64;

  const f32x4 z4 = {0.f,0.f,0.f,0.f};
  f32x4 acc[2][4];
  #pragma unroll
  for (int i=0;i<2;i++)
    #pragma unroll
    for (int j=0;j<4;j++) acc[i][j] = z4;

  for (int kt=0; kt<16; kt++){
    __syncthreads();
    #pragma unroll
    for (int i=0;i<4;i++){
      int row0 = wv*32 + i*8;
      int row  = row0 + (lane>>3);
      int col  = ((lane&7) ^ (row&7)) * 8;
      gload16(Ctx + (size_t)(bm+row)*1024 + kt*64 + col, Asm + row0*64);
    }
    #pragma unroll
    for (int i=0;i<2;i++){
      int row0 = wv*16 + i*8;
      int row  = row0 + (lane>>3);
      int col  = ((lane&7) ^ (row&7)) * 8;
      gload16(WoT + (size_t)(bn+row)*1024 + kt*64 + col, Bsm + row0*64);
    }
    __syncthreads();
    #pragma unroll
    for (int kc=0;kc<2;kc++){
      short8 af[2], bf[4];
      #pragma unroll
      for (int i=0;i<2;i++){
        int ra = wm + i*16 + (lane&15);
        af[i] = *(const short8*)((const char*)Asm + ra*128 + ((kc*64 + ((lane>>4)*16)) ^ ((ra&7)<<4)));
      }
      #pragma unroll
      for (int j=0;j<4;j++){
        int rb = j*16 + (lane&15);
        bf[j] = *(const short8*)((const char*)Bsm + rb*128 + ((kc*64 + ((lane>>4)*16)) ^ ((rb&7)<<4)));
      }
      #pragma unroll
      for (int i=0;i<2;i++)
        #pragma unroll
        for (int j=0;j<4;j++)
          acc[i][j] = MFMA16(af[i], bf[j], acc[i][j]);
    }
  }

  #pragma unroll
  for (int i=0;i<2;i++){
    #pragma unroll
    for (int j=0;j<4;j++){
      #pragma unroll
      for (int r=0;r<4;r++){
        int m = bm + wm + i*16 + ((lane>>4)*4) + r;
        int n = bn + j*16 + (lane&15);
        out[(size_t)m*1024 + n] = acc[i][j][r] + bias[n];
      }
    }
  }
}

// ---------------- launch ----------------
extern "C" void kernel_launch(void* const* d_in, const int* in_sizes, int n_in,
                              void* d_out, int out_size, void* d_ws, size_t ws_size,
                              hipStream_t stream) {
  const float* query = (const float*)d_in[0];
  const float* key   = (const float*)d_in[1];
  const float* value = (const float*)d_in[2];
  const float* amask = (const float*)d_in[3];
  const float* sup   = (const float*)d_in[4];
  const float* Wq    = (const float*)d_in[5];
  const float* Wk    = (const float*)d_in[6];
  const float* Wv    = (const float*)d_in[7];
  const float* Wo    = (const float*)d_in[8];
  const float* bo    = (const float*)d_in[9];
  // d_in[10] = causal_mask (deterministic triu(1)) -- applied analytically.

  char* ws = (char*)d_ws;
  const size_t MB = 1u<<20;
  short* WqT = (short*)(ws + 0*MB);
  short* WkT = (short*)(ws + 2*MB);
  short* WvT = (short*)(ws + 4*MB);
  short* WoT = (short*)(ws + 6*MB);
  short* Qb  = (short*)(ws + 8*MB);    // bf16 [4096][1024]
  short* Kb  = (short*)(ws + 16*MB);
  short* Vb  = (short*)(ws + 24*MB);
  short* Qh  = (short*)(ws + 32*MB);   // [64][1024][64]
  short* Kh  = (short*)(ws + 40*MB);   // [64][1024][64]
  short* VTh = (short*)(ws + 48*MB);   // [64][64][1024]
  short* Ctx = (short*)(ws + 56*MB);   // [4096][1024]
  // 64 MB of d_ws total

  wtrans_kernel<<<dim3(32,32,4), dim3(32,8), 0, stream>>>(Wq,Wk,Wv,Wo, WqT,WkT,WvT,WoT);
  cvt_kernel<<<dim3(2048,3), 256, 0, stream>>>(query,key,value, Qb,Kb,Vb);
  gemm_qkv_kernel<<<dim3(8,32,3), 256, 0, stream>>>(Qb,Kb,Vb, WqT,WkT,WvT, Qh,Kh,VTh);
  attn_kernel<<<dim3(16,64), 256, 0, stream>>>(Qh, Kh, VTh, amask, sup, Ctx);
  gemm_out_kernel<<<dim3(16,32), 256, 0, stream>>>(Ctx, WoT, (float*)d_out, bo);
}